// Round 5
// baseline (685.423 us; speedup 1.0000x reference)
//
#include <hip/hip_runtime.h>

using u16 = unsigned short;
using f32x4 = __attribute__((ext_vector_type(4))) float;
using s16x8 = __attribute__((ext_vector_type(8))) short;
using u32x4 = __attribute__((ext_vector_type(4))) unsigned int;

// ---- problem constants (T=512, B=64, D=256, H=256) ----
#define TT 512
#define BB 64
#define ALPHA 0.9f
// output element offsets (FP32 elements) in d_out, concatenated return order:
// spikes [513,64,256], preds [512,64,256], probs [512,64,256], v_T [64,256], s_T [64,256]
#define SPIKES_OFF 0L
#define PREDS_OFF  8404992L
#define PROBS_OFF  16793600L
#define VT_OFF     25182208L
#define ST_OFF     25198592L

__device__ __forceinline__ u16 f2bf(float f) {
    union { float f; unsigned int i; } cv; cv.f = f;
    unsigned int x = cv.i;
    return (u16)((x + 0x7FFFu + ((x >> 16) & 1u)) >> 16);   // RNE
}

// Packed RNE fp32x2 -> bf16x2 in ONE instruction (no builtin on gfx950; m240).
__device__ __forceinline__ unsigned int cvt_pk_bf16(float lo, float hi) {
    unsigned int r;
    asm("v_cvt_pk_bf16_f32 %0, %1, %2" : "=v"(r) : "v"(lo), "v"(hi));
    return r;
}

// Launder a value into a guaranteed-zero the compiler cannot fold away.
// Used to make LDS data-read addresses DATA-DEPEND on an observed flag value,
// so the read provably issues after the flag load (no fences needed).
__device__ __forceinline__ unsigned and0(unsigned x) {
    unsigned r;
    asm("v_and_b32 %0, 0, %1" : "=v"(r) : "v"(x));
    return r;
}

// ---------------------------------------------------------------------------
// One-time: WT[mat] bf16 [n][k] <- W fp32 [k][n], for W_in / W_rec / W_out.
// ---------------------------------------------------------------------------
__global__ void transpose_w(const float* __restrict__ W_in,
                            const float* __restrict__ W_rec,
                            const float* __restrict__ W_out,
                            u16* __restrict__ WT)
{
    const float* src = (blockIdx.x == 0) ? W_in : (blockIdx.x == 1) ? W_rec : W_out;
    u16* dst = WT + (long)blockIdx.x * 65536;
    const int n = threadIdx.x;
    for (int k0 = 0; k0 < 256; k0 += 8) {
        unsigned int dw[4];
        #pragma unroll
        for (int j = 0; j < 4; ++j)
            dw[j] = cvt_pk_bf16(src[(k0 + 2*j)*256 + n], src[(k0 + 2*j + 1)*256 + n]);
        u32x4 val = { dw[0], dw[1], dw[2], dw[3] };
        *(u32x4*)&dst[n*256 + k0] = val;
    }
}

// ---------------------------------------------------------------------------
// GEMM: C[m][n] = sum_k A[m][k] * W[k][n] (+ bias[n]).  A fp32 -> bf16 LDS,
// WT bf16 [n][k] -> dwordx4 fragment loads.  C fp32.
// COPY_A: also mirror the raw A tile to copyDst (gemm2 materializes
// spikes[1:] = probs while it reads them anyway).
// mfma(wfrag, xfrag, acc) -> lane holds D[m = mbase+(lane&15)][n = nbase+quad*4+r].
// wg 256 thr = 4 waves; tile M=64, all N=256; wave w -> n in [w*64, w*64+64).
// ---------------------------------------------------------------------------
template <bool ADD_BIAS, bool COPY_A>
__global__ __launch_bounds__(256, 2)
void gemm_rows(const float* __restrict__ A, const u16* __restrict__ WT,
               const float* __restrict__ bias, float* __restrict__ C,
               float* __restrict__ copyDst)
{
    const int tid  = threadIdx.x;
    const int lane = tid & 63;
    const int wave = tid >> 6;
    const int l15  = lane & 15;
    const int quad = lane >> 4;
    const long mblock = (long)blockIdx.x * 64;

    __shared__ u16 Alds[64][264];   // bf16 tile, +8 pad per row

    #pragma unroll
    for (int i = 0; i < 16; ++i) {
        int q = i*256 + tid;
        int r = q >> 6;
        int c = (q & 63) << 2;
        f32x4 a4 = *(const f32x4*)&A[(mblock + r)*256 + c];
        if (COPY_A)
            *(f32x4*)&copyDst[(mblock + r)*256 + c] = a4;
        uint2 val;
        val.x = cvt_pk_bf16(a4[0], a4[1]);
        val.y = cvt_pk_bf16(a4[2], a4[3]);
        *(uint2*)&Alds[r][c] = val;
    }

    s16x8 wfrag[4][8];
    const int nbase = wave * 64;
    #pragma unroll
    for (int nt = 0; nt < 4; ++nt)
        #pragma unroll
        for (int kt = 0; kt < 8; ++kt)
            wfrag[nt][kt] = *(const s16x8*)&WT[(nbase + nt*16 + l15)*256 + kt*32 + quad*8];

    __syncthreads();

    f32x4 acc[4][4] = {};   // [mt][nt]
    #pragma unroll
    for (int kt = 0; kt < 8; ++kt) {
        s16x8 xfrag[4];
        #pragma unroll
        for (int mt = 0; mt < 4; ++mt)
            xfrag[mt] = *(const s16x8*)&Alds[mt*16 + l15][kt*32 + quad*8];
        #pragma unroll
        for (int mt = 0; mt < 4; ++mt)
            #pragma unroll
            for (int nt = 0; nt < 4; ++nt)
                acc[mt][nt] = __builtin_amdgcn_mfma_f32_16x16x32_bf16(
                    wfrag[nt][kt], xfrag[mt], acc[mt][nt], 0, 0, 0);
    }

    #pragma unroll
    for (int mt = 0; mt < 4; ++mt) {
        long m = mblock + mt*16 + l15;
        #pragma unroll
        for (int nt = 0; nt < 4; ++nt) {
            int n = nbase + nt*16 + quad*4;
            f32x4 r = acc[mt][nt];
            if (ADD_BIAS) {
                f32x4 bb = *(const f32x4*)&bias[n];
                r[0] += bb[0]; r[1] += bb[1]; r[2] += bb[2]; r[3] += bb[3];
            }
            *(f32x4*)&C[m*256 + n] = r;
        }
    }
}

// ---------------------------------------------------------------------------
// MFMA recurrence. 4 WGs x 512 thr (8 waves => 2 waves/SIMD); WG = 16 batches.
// Per step: v = alpha*v + xin + s @ W_rec ; s = sigmoid(v).
//
// Round-5 delta vs round 4 (386 us): BARRIER REMOVED -> per-slice flag sync.
// Round-4 post-mortem: swizzle was neutral and the conflict counter is a
// benign structural artifact; the real cost is the per-step s_barrier CONVOY:
// all 8 waves leave the barrier together, storm the LDS port (570-cyc drain),
// then all do MFMA, then all do sigmoid -> phases serialize (~1814 cyc/step).
//
// Structure: sfrag[kt] (k in [32kt,32kt+32)) is produced by exactly wave kt.
//  * wave w consumes slices in ring order kt=(w+i)&7: OWN slice first (always
//    ready, MFMAs start immediately); inter-wave waits pushed down the chain.
//  * publish: ds_write slice -> s_waitcnt lgkmcnt(0) -> flags[wb][w] = t+1.
//  * consume: one flag snapshot per step (2 x b128, uniform broadcast);
//    spin only on slices whose snapshot bit is stale.  Every data read's
//    address adds and0(observed flag) -> hardware-ordered after the flag load.
//  * 2-buffer ping-pong stays safe without a barrier: a wave writing s(t+1)
//    observed flags==t from ALL waves, which implies every wave drained its
//    s(t-1) reads (flag is set after lgkmcnt(0)).  Max skew = 1 step.
// Waves drift instead of convoying: 8 waves start on 8 different slices, the
// LDS port / MFMA / VALU phases decorrelate and overlap across waves.
// Lane holds D[n = nbase+nt*16+quad*4+r][batch = lane&15] (HW-verified r4).
// Global stores never waited on; xin prefetched 2 steps ahead; only probs
// written per step (spikes[1:] materialized by gemm2's COPY_A).
// ---------------------------------------------------------------------------
__global__ __launch_bounds__(512, 2)
void recurrence_mfma(const float* __restrict__ Xin, const float* __restrict__ spike0,
                     const float* __restrict__ v0, const u16* __restrict__ WTrec,
                     float* __restrict__ out)
{
    const int tid  = threadIdx.x;
    const int lane = tid & 63;
    const int wave = tid >> 6;          // 0..7
    const int l15  = lane & 15;
    const int quad = lane >> 4;
    const int B0   = blockIdx.x * 16;
    const int nbase = wave * 32;        // 32-wide h slice per wave
    const int hq = quad * 4;

    __shared__ u16 s_lds[2 * 16 * 256];            // 16 KB, flat swizzled
    __shared__ __align__(16) unsigned s_flags[2][8];  // [buf][producer wave]

    const int wxor = l15 & 7;
    const int rowb = l15 * 256;

    // ring order: slice i -> kt = (wave+i)&7 ; slice 0 is the wave's OWN.
    int ktR[8], rOffR[8];
    #pragma unroll
    for (int i = 0; i < 8; ++i) {
        ktR[i] = (wave + i) & 7;
        rOffR[i] = rowb + (((ktR[i]*4 + quad) ^ wxor) << 3);
    }
    // write offsets (u16 units): uint2 at h0 = nbase + nt*16 + quad*4
    int wOff[2];
    #pragma unroll
    for (int nt = 0; nt < 2; ++nt)
        wOff[nt] = rowb + ((((nbase >> 3) + nt*2 + (quad >> 1)) ^ wxor) << 3)
                        + ((quad & 1) << 2);

    // W_rec^T A-fragments in RING order (64 VGPRs), so MFMA i uses wfragR[nt][i]
    // with a static index (no runtime register-array indexing).
    s16x8 wfragR[2][8];
    #pragma unroll
    for (int i = 0; i < 8; ++i)
        #pragma unroll
        for (int nt = 0; nt < 2; ++nt)
            wfragR[nt][i] = *(const s16x8*)&WTrec[(nbase + nt*16 + l15)*256 + ktR[i]*32 + quad*8];

    // init flags + s buffer 0 from spike0 (swizzled writes); emit spikes[0]
    if (tid < 16) ((unsigned*)s_flags)[tid] = 0u;   // buf0 "step 0 resident"
    #pragma unroll
    for (int i = 0; i < 8; ++i) {
        int idx = i*512 + tid;
        int m = idx >> 8, h = idx & 255;
        float s0v = spike0[(B0 + m)*256 + h];
        out[SPIKES_OFF + (B0 + m)*256 + h] = s0v;
        s_lds[m*256 + (((h >> 3) ^ (m & 7)) << 3) + (h & 7)] = f2bf(s0v);
    }

    const long lrow = (long)(B0 + l15) * 256;
    f32x4 v[2], xinA[2], xinB[2];
    #pragma unroll
    for (int nt = 0; nt < 2; ++nt) {
        const int h = nbase + nt*16 + hq;
        v[nt]    = *(const f32x4*)&v0[lrow + h];
        xinA[nt] = *(const f32x4*)&Xin[lrow + h];           // t=0
        xinB[nt] = *(const f32x4*)&Xin[16384 + lrow + h];   // t=1
    }
    // walking pointers: one 64-bit bump (+64 KB) per step; nt -> imm offset.
    const float* xin_p = Xin + 2L*16384 + lrow + nbase + hq;   // prefetch t=2
    float*       pr_p  = out + PROBS_OFF + lrow + nbase + hq;  // probs t=0

    __syncthreads();   // one-time: covers spike0 LDS init + flag init

#define GET_SLICE(i_)                                                         \
    if (!((rdy >> ktR[i_]) & 1)) {                                            \
        volatile unsigned* f_ = (volatile unsigned*)&s_flags[rb][ktR[i_]];    \
        unsigned fv_; do { fv_ = *f_; } while (fv_ != want);                  \
        z += and0(fv_);                                                       \
    }                                                                         \
    sfrag[i_] = *(const s16x8*)(s_lds + ldsbase + rOffR[i_] + z);

#define DO_MFMA(i_)                                                           \
    acc[0] = __builtin_amdgcn_mfma_f32_16x16x32_bf16(wfragR[0][i_], sfrag[i_], acc[0], 0, 0, 0); \
    acc[1] = __builtin_amdgcn_mfma_f32_16x16x32_bf16(wfragR[1][i_], sfrag[i_], acc[1], 0, 0, 0);

    #pragma unroll 1
    for (int t2 = 0; t2 < TT; t2 += 2) {
        #pragma unroll
        for (int half = 0; half < 2; ++half) {
            const int rb = half, wb = half ^ 1;   // t2 even -> (t&1) == half
            const int ldsbase = rb << 12;         // u16 offset of read buffer
            const unsigned want = (unsigned)(t2 + half);

            // xin prefetch for t+2 (vmcnt decoupling; tail over-read lands in
            // the probs region: valid memory, never consumed)
            f32x4 xnew[2];
            xnew[0] = *(const f32x4*)&xin_p[0];
            xnew[1] = *(const f32x4*)&xin_p[16];

            // own slice first -- no flag needed (we published it last step)
            s16x8 sfrag[8];
            sfrag[0] = *(const s16x8*)(s_lds + ldsbase + rOffR[0]);

            // one flag snapshot per step (uniform broadcast reads)
            u32x4 snA = *(const u32x4*)&s_flags[rb][0];
            u32x4 snB = *(const u32x4*)&s_flags[rb][4];
            unsigned rdy = (snA[0] == want ?   1u : 0u) | (snA[1] == want ?   2u : 0u)
                         | (snA[2] == want ?   4u : 0u) | (snA[3] == want ?   8u : 0u)
                         | (snB[0] == want ?  16u : 0u) | (snB[1] == want ?  32u : 0u)
                         | (snB[2] == want ?  64u : 0u) | (snB[3] == want ? 128u : 0u);
            unsigned z = and0(rdy);   // 0, but data-depends on the snapshot

            // acc = alpha*v + xin (consume this step's 2-ahead prefetch)
            f32x4 acc[2];
            #pragma unroll
            for (int nt = 0; nt < 2; ++nt)
                #pragma unroll
                for (int c = 0; c < 4; ++c)
                    acc[nt][c] = fmaf(ALPHA, v[nt][c],
                                      half == 0 ? xinA[nt][c] : xinB[nt][c]);
            #pragma unroll
            for (int nt = 0; nt < 2; ++nt) {
                if (half == 0) xinA[nt] = xnew[nt]; else xinB[nt] = xnew[nt];
            }

            // ring-pipelined: reads run 2 slices ahead of MFMA consumption
            GET_SLICE(1); GET_SLICE(2);
            DO_MFMA(0);
            GET_SLICE(3); DO_MFMA(1);
            GET_SLICE(4); DO_MFMA(2);
            GET_SLICE(5); DO_MFMA(3);
            GET_SLICE(6); DO_MFMA(4);
            GET_SLICE(7); DO_MFMA(5);
            DO_MFMA(6);   DO_MFMA(7);

            // sigmoid -> s slice (publish ASAP: inter-wave critical path)
            f32x4 p[2];
            #pragma unroll
            for (int nt = 0; nt < 2; ++nt) {
                #pragma unroll
                for (int c = 0; c < 4; ++c)
                    p[nt][c] = __builtin_amdgcn_rcpf(1.0f + __expf(-acc[nt][c]));
                uint2 sw;
                sw.x = cvt_pk_bf16(p[nt][0], p[nt][1]);
                sw.y = cvt_pk_bf16(p[nt][2], p[nt][3]);
                *(uint2*)(s_lds + (wb << 12) + wOff[nt]) = sw;
            }
            // drain slice writes, then raise our flag (one lane)
            asm volatile("s_waitcnt lgkmcnt(0)" ::: "memory");
            if (lane == 0)
                *(volatile unsigned*)&s_flags[wb][wave] = want + 1;

            // off-path: v update, probs store, pointer bumps
            #pragma unroll
            for (int nt = 0; nt < 2; ++nt) {
                v[nt] = acc[nt];
                *(f32x4*)&pr_p[nt*16] = p[nt];
            }
            xin_p += 16384;
            pr_p  += 16384;
        }
    }
#undef GET_SLICE
#undef DO_MFMA

    // tails: v_T and s_T = sigmoid(v_T) (recomputed once; no per-step branch)
    #pragma unroll
    for (int nt = 0; nt < 2; ++nt) {
        const int h = nbase + nt*16 + hq;
        f32x4 vv = v[nt], p;
        #pragma unroll
        for (int c = 0; c < 4; ++c)
            p[c] = __builtin_amdgcn_rcpf(1.0f + __expf(-vv[c]));
        *(f32x4*)&out[VT_OFF + lrow + h] = vv;
        *(f32x4*)&out[ST_OFF + lrow + h] = p;
    }
}

// ---------------------------------------------------------------------------
extern "C" void kernel_launch(void* const* d_in, const int* in_sizes, int n_in,
                              void* d_out, int out_size, void* d_ws, size_t ws_size,
                              hipStream_t stream) {
    const float* inputs = (const float*)d_in[0];   // [512,64,256]
    const float* spike0 = (const float*)d_in[1];   // [64,256]
    const float* v0     = (const float*)d_in[2];   // [64,256]
    const float* W_in   = (const float*)d_in[3];   // [256,256]
    const float* W_rec  = (const float*)d_in[4];   // [256,256]
    const float* W_out  = (const float*)d_in[5];   // [256,256]
    const float* bvec   = (const float*)d_in[6];   // [256]
    float* out = (float*)d_out;

    // d_ws: 3 transposed bf16 weight matrices, 384 KB.
    u16* WT = (u16*)d_ws;
    u16* WTin  = WT;
    u16* WTrec = WT + 65536;
    u16* WTout = WT + 131072;

    // Xin (fp32 [32768,256]) staged in the preds output region; overwritten by
    // gemm2 after the recurrence consumes it.
    float* Xin = out + PREDS_OFF;

    transpose_w<<<3, 256, 0, stream>>>(W_in, W_rec, W_out, WT);
    gemm_rows<true, false><<<512, 256, 0, stream>>>(inputs, WTin, bvec, Xin, nullptr);
    recurrence_mfma<<<4, 512, 0, stream>>>(Xin, spike0, v0, WTrec, out);
    // gemm2 reads probs as A (== spikes[1:]) and mirrors the tile into the
    // spikes region while staging it -- recurrence no longer writes spikes.
    gemm_rows<false, true><<<512, 256, 0, stream>>>(out + PROBS_OFF, WTout, bvec,
                                                    out + PREDS_OFF, out + 16384);
}

// Round 6
// 557.427 us; speedup vs baseline: 1.2296x; 1.2296x over previous
//
#include <hip/hip_runtime.h>

using u16 = unsigned short;
using f32x4 = __attribute__((ext_vector_type(4))) float;
using s16x8 = __attribute__((ext_vector_type(8))) short;
using u32x4 = __attribute__((ext_vector_type(4))) unsigned int;

// ---- problem constants (T=512, B=64, D=256, H=256) ----
#define TT 512
#define BB 64
#define ALPHA 0.9f
// output element offsets (FP32 elements) in d_out, concatenated return order:
// spikes [513,64,256], preds [512,64,256], probs [512,64,256], v_T [64,256], s_T [64,256]
#define SPIKES_OFF 0L
#define PREDS_OFF  8404992L
#define PROBS_OFF  16793600L
#define VT_OFF     25182208L
#define ST_OFF     25198592L

__device__ __forceinline__ u16 f2bf(float f) {
    union { float f; unsigned int i; } cv; cv.f = f;
    unsigned int x = cv.i;
    return (u16)((x + 0x7FFFu + ((x >> 16) & 1u)) >> 16);   // RNE
}

// Packed RNE fp32x2 -> bf16x2 in ONE instruction (no builtin on gfx950; m240).
__device__ __forceinline__ unsigned int cvt_pk_bf16(float lo, float hi) {
    unsigned int r;
    asm("v_cvt_pk_bf16_f32 %0, %1, %2" : "=v"(r) : "v"(lo), "v"(hi));
    return r;
}

// LDS-only barrier: waits ds ops, NOT the in-flight global stores/loads.
// __syncthreads() would emit s_waitcnt vmcnt(0) and drain every global store
// + prefetch each step.
__device__ __forceinline__ void lds_barrier() {
    __asm__ volatile("s_waitcnt lgkmcnt(0)\n\ts_barrier" ::: "memory");
}

// ---------------------------------------------------------------------------
// One-time: WT[mat] bf16 [n][k] <- W fp32 [k][n], for W_in / W_rec / W_out.
// ---------------------------------------------------------------------------
__global__ void transpose_w(const float* __restrict__ W_in,
                            const float* __restrict__ W_rec,
                            const float* __restrict__ W_out,
                            u16* __restrict__ WT)
{
    const float* src = (blockIdx.x == 0) ? W_in : (blockIdx.x == 1) ? W_rec : W_out;
    u16* dst = WT + (long)blockIdx.x * 65536;
    const int n = threadIdx.x;
    for (int k0 = 0; k0 < 256; k0 += 8) {
        unsigned int dw[4];
        #pragma unroll
        for (int j = 0; j < 4; ++j)
            dw[j] = cvt_pk_bf16(src[(k0 + 2*j)*256 + n], src[(k0 + 2*j + 1)*256 + n]);
        u32x4 val = { dw[0], dw[1], dw[2], dw[3] };
        *(u32x4*)&dst[n*256 + k0] = val;
    }
}

// ---------------------------------------------------------------------------
// GEMM: C[m][n] = sum_k A[m][k] * W[k][n] (+ bias[n]).  A fp32 -> bf16 LDS,
// WT bf16 [n][k] -> dwordx4 fragment loads.  C fp32.
// COPY_A: also mirror the raw A tile to copyDst (gemm2 materializes
// spikes[1:] = probs while it reads them anyway).
// mfma(wfrag, xfrag, acc) -> lane holds D[m = mbase+(lane&15)][n = nbase+quad*4+r].
// wg 256 thr = 4 waves; tile M=64, all N=256; wave w -> n in [w*64, w*64+64).
// ---------------------------------------------------------------------------
template <bool ADD_BIAS, bool COPY_A>
__global__ __launch_bounds__(256, 2)
void gemm_rows(const float* __restrict__ A, const u16* __restrict__ WT,
               const float* __restrict__ bias, float* __restrict__ C,
               float* __restrict__ copyDst)
{
    const int tid  = threadIdx.x;
    const int lane = tid & 63;
    const int wave = tid >> 6;
    const int l15  = lane & 15;
    const int quad = lane >> 4;
    const long mblock = (long)blockIdx.x * 64;

    __shared__ u16 Alds[64][264];   // bf16 tile, +8 pad per row

    #pragma unroll
    for (int i = 0; i < 16; ++i) {
        int q = i*256 + tid;
        int r = q >> 6;
        int c = (q & 63) << 2;
        f32x4 a4 = *(const f32x4*)&A[(mblock + r)*256 + c];
        if (COPY_A)
            *(f32x4*)&copyDst[(mblock + r)*256 + c] = a4;
        uint2 val;
        val.x = cvt_pk_bf16(a4[0], a4[1]);
        val.y = cvt_pk_bf16(a4[2], a4[3]);
        *(uint2*)&Alds[r][c] = val;
    }

    s16x8 wfrag[4][8];
    const int nbase = wave * 64;
    #pragma unroll
    for (int nt = 0; nt < 4; ++nt)
        #pragma unroll
        for (int kt = 0; kt < 8; ++kt)
            wfrag[nt][kt] = *(const s16x8*)&WT[(nbase + nt*16 + l15)*256 + kt*32 + quad*8];

    __syncthreads();

    f32x4 acc[4][4] = {};   // [mt][nt]
    #pragma unroll
    for (int kt = 0; kt < 8; ++kt) {
        s16x8 xfrag[4];
        #pragma unroll
        for (int mt = 0; mt < 4; ++mt)
            xfrag[mt] = *(const s16x8*)&Alds[mt*16 + l15][kt*32 + quad*8];
        #pragma unroll
        for (int mt = 0; mt < 4; ++mt)
            #pragma unroll
            for (int nt = 0; nt < 4; ++nt)
                acc[mt][nt] = __builtin_amdgcn_mfma_f32_16x16x32_bf16(
                    wfrag[nt][kt], xfrag[mt], acc[mt][nt], 0, 0, 0);
    }

    #pragma unroll
    for (int mt = 0; mt < 4; ++mt) {
        long m = mblock + mt*16 + l15;
        #pragma unroll
        for (int nt = 0; nt < 4; ++nt) {
            int n = nbase + nt*16 + quad*4;
            f32x4 r = acc[mt][nt];
            if (ADD_BIAS) {
                f32x4 bb = *(const f32x4*)&bias[n];
                r[0] += bb[0]; r[1] += bb[1]; r[2] += bb[2]; r[3] += bb[3];
            }
            *(f32x4*)&C[m*256 + n] = r;
        }
    }
}

// ---------------------------------------------------------------------------
// MFMA recurrence. 4 WGs x 512 thr (8 waves => 2 waves/SIMD); WG = 16 batches.
// Per step: v = alpha*v + xin + s @ W_rec ; s = sigmoid(v).
//
// Round-6 delta vs round 4 (386 us, passed) -- critical-path register-dataflow
// trims only, sync protocol and LDS layout identical:
//  * IN-PLACE ACCUMULATOR: Astate = alpha*v + xin is computed at the END of
//    the previous step (overlaps sigmoid/barrier wait); post-barrier MFMAs
//    start as soon as sfrag[0] lands.  v[] copies eliminated (v_T taken from
//    the final sum regs).
//  * 4-WAY MFMA CHAIN SPLIT: per nt, kt0-3 accumulate into Astate, kt4-7
//    into a zero-seeded chain; combined with 4 v_add at the end.  Issue
//    interleaved 4-wide -> dep distance ~4 issues, covers MFMA latency.
//  * x4 UNROLL + 4-slot xin rotation: no xin register copies; all static.
//  * uint voffset walking addresses (SGPR base + 32b offset, 1 v_add/step)
//    for xin loads and probs stores.
//  * sfrag read order 0,4,1,5,2,6,3,7 so early chains' operands retire first
//    (LDS retires in-order).
// Lane holds D[n = nbase+nt*16+quad*4+r][batch = lane&15] (HW-verified r4).
// One raw lds_barrier per step; global stores never waited on; only probs
// written per step (spikes[1:] materialized by gemm2's COPY_A).
// ---------------------------------------------------------------------------
__global__ __launch_bounds__(512, 2)
void recurrence_mfma(const float* __restrict__ Xin, const float* __restrict__ spike0,
                     const float* __restrict__ v0, const u16* __restrict__ WTrec,
                     float* __restrict__ out)
{
    const int tid  = threadIdx.x;
    const int lane = tid & 63;
    const int wave = tid >> 6;          // 0..7
    const int l15  = lane & 15;
    const int quad = lane >> 4;
    const int B0   = blockIdx.x * 16;
    const int nbase = wave * 32;        // 32-wide h slice per wave
    const int hq = quad * 4;

    __shared__ u16 s_lds[2 * 16 * 256];   // 16 KB, flat swizzled

    const int wxor = l15 & 7;
    const int rowb = l15 * 256;
    // read offsets (u16 units): sfrag[kt] = 16B at k0 = kt*32 + quad*8
    int rOff[8];
    #pragma unroll
    for (int kt = 0; kt < 8; ++kt)
        rOff[kt] = rowb + (((kt*4 + quad) ^ wxor) << 3);
    // write offsets (u16 units): uint2 at h0 = nbase + nt*16 + quad*4
    int wOff[2];
    #pragma unroll
    for (int nt = 0; nt < 2; ++nt)
        wOff[nt] = rowb + ((((nbase >> 3) + nt*2 + (quad >> 1)) ^ wxor) << 3)
                        + ((quad & 1) << 2);

    // W_rec^T A-fragments, register-resident for all 512 steps (64 VGPRs)
    s16x8 wfrag[2][8];
    #pragma unroll
    for (int nt = 0; nt < 2; ++nt)
        #pragma unroll
        for (int kt = 0; kt < 8; ++kt)
            wfrag[nt][kt] = *(const s16x8*)&WTrec[(nbase + nt*16 + l15)*256 + kt*32 + quad*8];

    // init s buffer 0 from spike0 (swizzled writes); emit spikes[0]
    #pragma unroll
    for (int i = 0; i < 8; ++i) {
        int idx = i*512 + tid;
        int m = idx >> 8, h = idx & 255;
        float s0v = spike0[(B0 + m)*256 + h];
        out[SPIKES_OFF + (B0 + m)*256 + h] = s0v;
        s_lds[m*256 + (((h >> 3) ^ (m & 7)) << 3) + (h & 7)] = f2bf(s0v);
    }

    const long lrow = (long)(B0 + l15) * 256;
    const int  lvo  = (int)lrow + nbase + hq;   // per-lane element offset

    // Astate[nt] = alpha*v_t + xin_t  (C-in of the low MFMA chain)
    // xq[slot][nt]: 4-deep xin prefetch rotation, all indices static.
    f32x4 Astate[2], vfin[2], xq[4][2];
    #pragma unroll
    for (int slot = 0; slot < 4; ++slot)
        #pragma unroll
        for (int nt = 0; nt < 2; ++nt)
            xq[slot][nt] = *(const f32x4*)&Xin[(unsigned)(slot*16384 + lvo) + nt*16];
    #pragma unroll
    for (int nt = 0; nt < 2; ++nt) {
        f32x4 vv = *(const f32x4*)&v0[lrow + nbase + nt*16 + hq];
        #pragma unroll
        for (int c = 0; c < 4; ++c)
            Astate[nt][c] = fmaf(ALPHA, vv[c], xq[0][nt][c]);
    }
    const f32x4 z4 = { 0.0f, 0.0f, 0.0f, 0.0f };

    // walking uint offsets (SGPR base + 32b voffset form)
    unsigned xoff = (unsigned)(4*16384 + lvo);     // prefetch t=4
    unsigned poff = (unsigned)lvo;                 // probs t=0
    const float* probs_base = out + PROBS_OFF;

    __syncthreads();   // one-time full barrier (covers spike0 LDS init)

    #pragma unroll 1
    for (int t4 = 0; t4 < TT; t4 += 4) {
        #pragma unroll
        for (int half = 0; half < 4; ++half) {
            const int rb = half & 1, wb = rb ^ 1;
            const int ldsbase = rb << 12;

            // xin prefetch for t+4 into the slot consumed this step
            // (tail over-reads land in the probs region: valid, never consumed)
            f32x4 xnew[2];
            xnew[0] = *(const f32x4*)&Xin[xoff];
            xnew[1] = *(const f32x4*)&Xin[xoff + 16];

            // s B-fragments; order 0,4,1,5,... so chain heads retire first
            s16x8 sfrag[8];
            sfrag[0] = *(const s16x8*)(s_lds + ldsbase + rOff[0]);
            sfrag[4] = *(const s16x8*)(s_lds + ldsbase + rOff[4]);
            sfrag[1] = *(const s16x8*)(s_lds + ldsbase + rOff[1]);
            sfrag[5] = *(const s16x8*)(s_lds + ldsbase + rOff[5]);
            sfrag[2] = *(const s16x8*)(s_lds + ldsbase + rOff[2]);
            sfrag[6] = *(const s16x8*)(s_lds + ldsbase + rOff[6]);
            sfrag[3] = *(const s16x8*)(s_lds + ldsbase + rOff[3]);
            sfrag[7] = *(const s16x8*)(s_lds + ldsbase + rOff[7]);

            // 4 interleaved chains: AL[nt] (C-in=Astate, kt0-3),
            //                       AH[nt] (C-in=0,      kt4-7)
            f32x4 AL[2], AH[2];
            #pragma unroll
            for (int nt = 0; nt < 2; ++nt) {
                AL[nt] = __builtin_amdgcn_mfma_f32_16x16x32_bf16(
                             wfrag[nt][0], sfrag[0], Astate[nt], 0, 0, 0);
                AH[nt] = __builtin_amdgcn_mfma_f32_16x16x32_bf16(
                             wfrag[nt][4], sfrag[4], z4, 0, 0, 0);
            }
            #pragma unroll
            for (int k = 1; k < 4; ++k)
                #pragma unroll
                for (int nt = 0; nt < 2; ++nt) {
                    AL[nt] = __builtin_amdgcn_mfma_f32_16x16x32_bf16(
                                 wfrag[nt][k], sfrag[k], AL[nt], 0, 0, 0);
                    AH[nt] = __builtin_amdgcn_mfma_f32_16x16x32_bf16(
                                 wfrag[nt][k+4], sfrag[k+4], AH[nt], 0, 0, 0);
                }
            #pragma unroll
            for (int nt = 0; nt < 2; ++nt)
                #pragma unroll
                for (int c = 0; c < 4; ++c)
                    vfin[nt][c] = AL[nt][c] + AH[nt][c];

            // next step's Astate = alpha*v_{t+1} + xin_{t+1}: off the critical
            // path (overlaps sigmoid/barrier); then rotate the slot.
            #pragma unroll
            for (int nt = 0; nt < 2; ++nt) {
                const int nslot = (half + 1) & 3;
                #pragma unroll
                for (int c = 0; c < 4; ++c)
                    Astate[nt][c] = fmaf(ALPHA, vfin[nt][c], xq[nslot][nt][c]);
                xq[half][nt] = xnew[nt];
            }

            // sigmoid -> s (bf16 to LDS ASAP: inter-wave critical path)
            f32x4 p[2];
            #pragma unroll
            for (int nt = 0; nt < 2; ++nt) {
                #pragma unroll
                for (int c = 0; c < 4; ++c)
                    p[nt][c] = __builtin_amdgcn_rcpf(1.0f + __expf(-vfin[nt][c]));
                uint2 sw;
                sw.x = cvt_pk_bf16(p[nt][0], p[nt][1]);
                sw.y = cvt_pk_bf16(p[nt][2], p[nt][3]);
                *(uint2*)(s_lds + (wb << 12) + wOff[nt]) = sw;
            }
            // probs store (never waited on) + offset bumps
            *(f32x4*)&probs_base[poff]      = p[0];
            *(f32x4*)&probs_base[poff + 16] = p[1];
            xoff += 16384;
            poff += 16384;
            lds_barrier();   // LDS-only: no vmcnt drain of stores/prefetch
        }
    }

    // tails: v_T = vfin (last step), s_T = sigmoid(v_T)
    #pragma unroll
    for (int nt = 0; nt < 2; ++nt) {
        const int h = nbase + nt*16 + hq;
        f32x4 vv = vfin[nt], p;
        #pragma unroll
        for (int c = 0; c < 4; ++c)
            p[c] = __builtin_amdgcn_rcpf(1.0f + __expf(-vv[c]));
        *(f32x4*)&out[VT_OFF + lrow + h] = vv;
        *(f32x4*)&out[ST_OFF + lrow + h] = p;
    }
}

// ---------------------------------------------------------------------------
extern "C" void kernel_launch(void* const* d_in, const int* in_sizes, int n_in,
                              void* d_out, int out_size, void* d_ws, size_t ws_size,
                              hipStream_t stream) {
    const float* inputs = (const float*)d_in[0];   // [512,64,256]
    const float* spike0 = (const float*)d_in[1];   // [64,256]
    const float* v0     = (const float*)d_in[2];   // [64,256]
    const float* W_in   = (const float*)d_in[3];   // [256,256]
    const float* W_rec  = (const float*)d_in[4];   // [256,256]
    const float* W_out  = (const float*)d_in[5];   // [256,256]
    const float* bvec   = (const float*)d_in[6];   // [256]
    float* out = (float*)d_out;

    // d_ws: 3 transposed bf16 weight matrices, 384 KB.
    u16* WT = (u16*)d_ws;
    u16* WTin  = WT;
    u16* WTrec = WT + 65536;
    u16* WTout = WT + 131072;

    // Xin (fp32 [32768,256]) staged in the preds output region; overwritten by
    // gemm2 after the recurrence consumes it.
    float* Xin = out + PREDS_OFF;

    transpose_w<<<3, 256, 0, stream>>>(W_in, W_rec, W_out, WT);
    gemm_rows<true, false><<<512, 256, 0, stream>>>(inputs, WTin, bvec, Xin, nullptr);
    recurrence_mfma<<<4, 512, 0, stream>>>(Xin, spike0, v0, WTrec, out);
    // gemm2 reads probs as A (== spikes[1:]) and mirrors the tile into the
    // spikes region while staging it -- recurrence no longer writes spikes.
    gemm_rows<false, true><<<512, 256, 0, stream>>>(out + PROBS_OFF, WTout, bvec,
                                                    out + PREDS_OFF, out + 16384);
}